// Round 2
// baseline (79.039 us; speedup 1.0000x reference)
//
#include <hip/hip_runtime.h>
#include <cmath>

// ---------------------------------------------------------------------------
// NeighborAdjustingLoss v3: uniform-kernel split schedule.
//
// K1 cent_kernel   (B blocks): row-mean of memory bank (134 MB stream).
// K2 select_kernel (B blocks): sim-row top-k select (67 MB stream), NO cent
//    dependency; writes 32 (key,idx) u64 + header (kmin, p33key, diag).
// K3 finale_kernel (B/4 blocks, 1 wave/row): exclusion-aware cent min/max via
//    4096-bit LDS bitmap over the 16 KB L2-resident cent array, validated
//    finale math, fence+counter last-block deterministic mean.
//
// B=4096 (sim BxB), M=8192 (mem BxM), k<=63, fp32. Requires B==4096.
// ---------------------------------------------------------------------------

#define CAP 256    // candidate capacity; expected ~93 for N(0,1) rows
#define MAXIT 40   // u32-key bisection bound (1 pass in practice)

__device__ inline float wave_max_f(float x) {
#pragma unroll
    for (int off = 32; off > 0; off >>= 1) x = fmaxf(x, __shfl_xor(x, off, 64));
    return x;
}
__device__ inline float wave_min_f(float x) {
#pragma unroll
    for (int off = 32; off > 0; off >>= 1) x = fminf(x, __shfl_xor(x, off, 64));
    return x;
}
__device__ inline float wave_sum_f(float x) {
#pragma unroll
    for (int off = 32; off > 0; off >>= 1) x += __shfl_xor(x, off, 64);
    return x;
}
__device__ inline unsigned int wave_min_u32(unsigned int x) {
#pragma unroll
    for (int off = 32; off > 0; off >>= 1) {
        unsigned int o = (unsigned int)__shfl_xor((int)x, off, 64);
        x = (o < x) ? o : x;
    }
    return x;
}

// order-preserving float<->uint key
__device__ inline unsigned int f_to_key(float f) {
    unsigned int u = __float_as_uint(f);
    return u ^ ((u & 0x80000000u) ? 0xFFFFFFFFu : 0x80000000u);
}
__device__ inline float key_to_f(unsigned int key) {
    unsigned int u = key ^ ((key & 0x80000000u) ? 0x80000000u : 0xFFFFFFFFu);
    return __uint_as_float(u);
}

// ---- K1: centrality = row-mean of memory bank (8 loads in flight) ----
__global__ __launch_bounds__(256)
void cent_kernel(const float* __restrict__ mem, float* __restrict__ cent,
                 unsigned int* __restrict__ ctr, int M) {
    __shared__ float s[4];
    const int row = blockIdx.x;
    if (blockIdx.x == 0 && threadIdx.x == 0) ctr[0] = 0u;  // finale's ctr
    const float4* p = (const float4*)(mem + (size_t)row * M);
    const int n4 = M >> 2;
    float acc = 0.0f;
    int i = threadIdx.x;
    for (; i + 1792 < n4; i += 2048) {
        float4 q0 = p[i], q1 = p[i + 256], q2 = p[i + 512], q3 = p[i + 768];
        float4 q4 = p[i + 1024], q5 = p[i + 1280], q6 = p[i + 1536], q7 = p[i + 1792];
        acc += ((q0.x + q0.y) + (q0.z + q0.w)) + ((q1.x + q1.y) + (q1.z + q1.w))
             + ((q2.x + q2.y) + (q2.z + q2.w)) + ((q3.x + q3.y) + (q3.z + q3.w))
             + ((q4.x + q4.y) + (q4.z + q4.w)) + ((q5.x + q5.y) + (q5.z + q5.w))
             + ((q6.x + q6.y) + (q6.z + q6.w)) + ((q7.x + q7.y) + (q7.z + q7.w));
    }
    for (; i < n4; i += 256) {
        float4 q = p[i];
        acc += (q.x + q.y) + (q.z + q.w);
    }
    acc = wave_sum_f(acc);
    const int lane = threadIdx.x & 63, wid = threadIdx.x >> 6;
    if (lane == 0) s[wid] = acc;
    __syncthreads();
    if (threadIdx.x == 0) cent[row] = (s[0] + s[1] + s[2] + s[3]) / (float)M;
}

// ---- K2: sim-row top-k select (no cent dependency) ----
__global__ __launch_bounds__(256)
void select_kernel(const float* __restrict__ sim,
                   const int* __restrict__ knn,
                   uint4* __restrict__ hdr,
                   unsigned long long* __restrict__ selbuf,
                   int B) {
    __shared__ __align__(16) unsigned long long cand[CAP];
    __shared__ unsigned long long s_p33;
    __shared__ unsigned int s_kmin[4];
    __shared__ unsigned int s_cnt;
    __shared__ float s_diag;

    const int row = blockIdx.x, tid = threadIdx.x;
    const int lane = tid & 63, wid = tid >> 6;
    const int k = knn[0];

    // load row (float4-coalesced), order keys; diag -> key 0
    unsigned int keys[16];
    unsigned int kmin = 0xFFFFFFFFu;
    const float4* rp = (const float4*)(sim + (size_t)row * B);
#pragma unroll
    for (int c = 0; c < 4; ++c) {
        float4 q = rp[c * 256 + tid];
        float t[4] = {q.x, q.y, q.z, q.w};
#pragma unroll
        for (int m = 0; m < 4; ++m) {
            const int j = c * 1024 + tid * 4 + m;
            unsigned int key = f_to_key(t[m]);
            if (j == row) { s_diag = t[m]; key = 0u; }
            else if (key < kmin) kmin = key;
            keys[c * 4 + m] = key;
        }
    }
    { unsigned int w = wave_min_u32(kmin); if (lane == 0) s_kmin[wid] = w; }
    if (tid == 0) { s_cnt = 0; s_p33 = ((unsigned long long)1u) << 32; }

    // threshold-gather candidates (key > keyT); exact bisection fallback,
    // keys stay in VGPRs (no global re-read).
    unsigned int keyT = f_to_key(2.0f), loK = 0u, hiK = 0xFFFFFFFFu, cnt = 0;
    const unsigned int need = (unsigned int)k + 1u;
    for (int it = 0; it < MAXIT; ++it) {
        __syncthreads();                    // s_cnt (re)set visible
#pragma unroll
        for (int c = 0; c < 4; ++c) {
#pragma unroll
            for (int m = 0; m < 4; ++m) {
                const unsigned int key = keys[c * 4 + m];
                if (key > keyT) {           // diag key==0 never passes
                    const unsigned int pos = atomicAdd(&s_cnt, 1u);
                    if (pos < CAP)
                        cand[pos] = ((unsigned long long)key << 32) |
                                    (unsigned long long)(0xFFFFFFFFu -
                                        (unsigned int)(c * 1024 + tid * 4 + m));
                }
            }
        }
        __syncthreads();                    // cand/cnt visible
        cnt = s_cnt;
        if (cnt >= need && cnt <= CAP) break;
        if (cnt < need) { hiK = keyT; keyT = loK + ((keyT - loK) >> 1); }
        else            { loK = keyT; keyT = keyT + ((hiK - keyT) >> 1); }
        if (tid == 0) s_cnt = 0;
    }
    if (wid != 0) return;                   // waves 1-3 done

    // wave 0: exact all-pairs ranks, state in named VGPRs
    {
        const unsigned int n = min(cnt, (unsigned int)CAP);
        const unsigned int p0 = lane, p1 = lane + 64u, p2 = lane + 128u, p3 = lane + 192u;
        unsigned long long own0 = 0ull, own1 = 0ull, own2 = 0ull, own3 = 0ull;
        if (p0 < n) own0 = cand[p0];
        if (p1 < n) own1 = cand[p1];
        if (p2 < n) own2 = cand[p2];
        if (p3 < n) own3 = cand[p3];
        unsigned int r0 = 0, r1 = 0, r2 = 0, r3 = 0;
        const ulonglong2* c2 = (const ulonglong2*)cand;   // broadcast b128 reads
        const unsigned int np = n >> 1;
        for (unsigned int o = 0; o < np; ++o) {
            ulonglong2 pr = c2[o];
            r0 += (pr.x > own0) ? 1u : 0u; r0 += (pr.y > own0) ? 1u : 0u;
            r1 += (pr.x > own1) ? 1u : 0u; r1 += (pr.y > own1) ? 1u : 0u;
            r2 += (pr.x > own2) ? 1u : 0u; r2 += (pr.y > own2) ? 1u : 0u;
            r3 += (pr.x > own3) ? 1u : 0u; r3 += (pr.y > own3) ? 1u : 0u;
        }
        if (n & 1u) {
            unsigned long long x = cand[n - 1u];
            r0 += (x > own0) ? 1u : 0u; r1 += (x > own1) ? 1u : 0u;
            r2 += (x > own2) ? 1u : 0u; r3 += (x > own3) ? 1u : 0u;
        }
        const unsigned int uk = (unsigned int)k;
        // rank<k -> selbuf slot=rank; rank==k -> (k+1)-th largest (mx_s)
#define HANDLE(P, OWN, R)                                                     \
        if ((P) < n) {                                                        \
            if ((R) < uk) selbuf[(size_t)row * 64 + (R)] = (OWN);             \
            else if ((R) == uk) s_p33 = (OWN);                                \
        }
        HANDLE(p0, own0, r0)
        HANDLE(p1, own1, r1)
        HANDLE(p2, own2, r2)
        HANDLE(p3, own3, r3)
#undef HANDLE
        __builtin_amdgcn_wave_barrier();   // order s_p33 write vs read
        if (lane == 0) {
            const unsigned int kminb =
                min(min(s_kmin[0], s_kmin[1]), min(s_kmin[2], s_kmin[3]));
            uint4 h;
            h.x = kminb;                       // mn_s key (off-diag row min)
            h.y = (unsigned int)(s_p33 >> 32); // mx_s key ((k+1)-th largest)
            h.z = __float_as_uint(s_diag);
            h.w = cnt;
            hdr[row] = h;
        }
    }
}

// ---- K3: per-row finale, one wave per row (4 rows/block) ----
__global__ __launch_bounds__(256)
void finale_kernel(const float* __restrict__ cent,
                   const uint4* __restrict__ hdr,
                   const unsigned long long* __restrict__ selbuf,
                   const int* __restrict__ knn,
                   const float* __restrict__ temp_p,
                   float* __restrict__ per_row,
                   unsigned int* __restrict__ ctr,
                   float* __restrict__ out, int B) {
    __shared__ unsigned int bm[4 * 128];   // 4096-bit exclusion bitmap per wave
    __shared__ float s_red[4];
    __shared__ int s_last;

    const int tid = threadIdx.x, lane = tid & 63, wid = tid >> 6;
    const int row = (blockIdx.x << 2) + wid;
    const int k = knn[0];
    const float temp = temp_p[0];

    const uint4 h = hdr[row];
    const float mn_s = key_to_f(h.x);
    const float mx_s = key_to_f(h.y);
    const float sdiag = __uint_as_float(h.z);

    const bool act = (lane < k);
    const unsigned long long sel = act ? selbuf[(size_t)row * 64 + lane] : 0ull;
    const float sj = act ? key_to_f((unsigned int)(sel >> 32)) : -INFINITY;
    const int   j  = act ? (int)(0xFFFFFFFFu - (unsigned int)sel) : 0;
    const float cj = cent[j];

    // build exclusion bitmap: {row} U selected
    unsigned int* mybm = &bm[wid * 128];
    mybm[lane * 2] = 0u; mybm[lane * 2 + 1] = 0u;
    __builtin_amdgcn_wave_barrier();
    if (act) atomicOr(&mybm[((unsigned int)j) >> 5], 1u << (j & 31));
    if (lane == 0) atomicOr(&mybm[((unsigned int)row) >> 5], 1u << (row & 31));
    __builtin_amdgcn_wave_barrier();

    // exact min/max of cent over non-excluded positions
    float cmin = INFINITY, cmax = -INFINITY;
    const float4* c4 = (const float4*)cent;
#pragma unroll
    for (int it = 0; it < 16; ++it) {
        const float4 v = c4[it * 64 + lane];
        const unsigned int w = mybm[it * 8 + (lane >> 3)];   // broadcast-friendly
        const unsigned int nib = w >> ((lane & 7) * 4);
        if (!(nib & 1u)) { cmin = fminf(cmin, v.x); cmax = fmaxf(cmax, v.x); }
        if (!(nib & 2u)) { cmin = fminf(cmin, v.y); cmax = fmaxf(cmax, v.y); }
        if (!(nib & 4u)) { cmin = fminf(cmin, v.z); cmax = fmaxf(cmax, v.z); }
        if (!(nib & 8u)) { cmin = fminf(cmin, v.w); cmax = fmaxf(cmax, v.w); }
    }
    const float mn_c = wave_min_f(cmin);
    const float mx_c = wave_max_f(cmax);

    // finale (math identical to the validated kernel)
    float a = -INFINITY;
    if (act) {
        const float ns = (sj - mn_s) / (mx_s - mn_s);
        const float nc = (cj - mn_c) / (mx_c - mn_c);
        a = (ns - nc) * temp;
    }
    const float am   = wave_max_f(a);
    const float e    = act ? expf(a - am) : 0.0f;
    const float esum = wave_sum_f(e);
    const float pw   = e / esum;

    const float m2  = fmaxf(wave_max_f(sj), sdiag);
    const float ex  = act ? expf(sj - m2) : 0.0f;
    const float lse = m2 + logf(wave_sum_f(ex) + expf(sdiag - m2));

    const float num = wave_sum_f(act ? pw * (sj - lse) : 0.0f) + (sdiag - lse);
    const float den = 1.0f + wave_sum_f(pw);
    if (lane == 0) per_row[row] = -num / den;

    // fence+counter last-block final mean (deterministic tree, device scope)
    __syncthreads();                 // all 4 per_row stores drained
    if (tid == 0) {
        __threadfence();             // agent release (cross-XCD wb)
        const unsigned int prev = atomicAdd(ctr, 1u);
        s_last = (prev == (unsigned int)(gridDim.x - 1u)) ? 1 : 0;
    }
    __syncthreads();
    if (s_last) {
        __threadfence();             // agent acquire (cross-XCD inv)
        float acc = 0.0f;
        const float4* p = (const float4*)per_row;
        const int n4 = B >> 2;
        for (int i = tid; i < n4; i += 256) {
            float4 q = p[i];
            acc += (q.x + q.y) + (q.z + q.w);
        }
        acc = wave_sum_f(acc);
        if (lane == 0) s_red[wid] = acc;
        __syncthreads();
        if (tid == 0) out[0] = (s_red[0] + s_red[1] + s_red[2] + s_red[3]) / (float)B;
    }
}

extern "C" void kernel_launch(void* const* d_in, const int* in_sizes, int n_in,
                              void* d_out, int out_size, void* d_ws, size_t ws_size,
                              hipStream_t stream) {
    const float* sim  = (const float*)d_in[0];
    const float* mem  = (const float*)d_in[1];
    const int*   knn  = (const int*)d_in[2];
    const float* temp = (const float*)d_in[3];
    float* out = (float*)d_out;

    char* ws = (char*)d_ws;
    float*              cent    = (float*)ws;                       // 16 KB
    float*              per_row = (float*)(ws + 16384);             // 16 KB
    unsigned int*       ctr     = (unsigned int*)(ws + 32768);      // 4 B
    uint4*              hdr     = (uint4*)(ws + 49152);             // 64 KB
    unsigned long long* selbuf  = (unsigned long long*)(ws + 114688); // 2 MB

    const int B = (int)(std::sqrt((double)in_sizes[0]) + 0.5);
    const int M = in_sizes[1] / B;

    cent_kernel<<<B, 256, 0, stream>>>(mem, cent, ctr, M);
    select_kernel<<<B, 256, 0, stream>>>(sim, knn, hdr, selbuf, B);
    finale_kernel<<<B / 4, 256, 0, stream>>>(cent, hdr, selbuf, knn, temp, per_row, ctr, out, B);
}

// Round 3
// 55.135 us; speedup vs baseline: 1.4336x; 1.4336x over previous
//
#include <hip/hip_runtime.h>
#include <cmath>

// ---------------------------------------------------------------------------
// NeighborAdjustingLoss v4: v0 (verified 56.3us) + block-wide rank tail.
// Single change vs v0: the exact all-pairs rank over candidates is computed
// by ALL 256 threads (thread t owns cand[t]) instead of wave 0 only -- the
// 1-wave tail was the latency bottleneck (evidence: select ran 77us with
// 1.3 MB HBM traffic in v2's rocprof replay => issue-bound, not BW-bound).
// B=4096 (sim BxB), M=8192 (mem BxM), k<=63, fp32.
// ---------------------------------------------------------------------------

#define CAP 256    // candidate capacity; expected ~93 for N(0,1) rows (>17 sigma)
#define MAXIT 40   // u32-key bisection bound (1 pass in practice)

__device__ inline float wave_max_f(float x) {
#pragma unroll
    for (int off = 32; off > 0; off >>= 1) x = fmaxf(x, __shfl_xor(x, off, 64));
    return x;
}
__device__ inline float wave_min_f(float x) {
#pragma unroll
    for (int off = 32; off > 0; off >>= 1) x = fminf(x, __shfl_xor(x, off, 64));
    return x;
}
__device__ inline float wave_sum_f(float x) {
#pragma unroll
    for (int off = 32; off > 0; off >>= 1) x += __shfl_xor(x, off, 64);
    return x;
}
__device__ inline unsigned int wave_min_u32(unsigned int x) {
#pragma unroll
    for (int off = 32; off > 0; off >>= 1) {
        unsigned int o = (unsigned int)__shfl_xor((int)x, off, 64);
        x = (o < x) ? o : x;
    }
    return x;
}

// order-preserving float<->uint key
__device__ inline unsigned int f_to_key(float f) {
    unsigned int u = __float_as_uint(f);
    return u ^ ((u & 0x80000000u) ? 0xFFFFFFFFu : 0x80000000u);
}
__device__ inline float key_to_f(unsigned int key) {
    unsigned int u = key ^ ((key & 0x80000000u) ? 0x80000000u : 0xFFFFFFFFu);
    return __uint_as_float(u);
}

// ---- centrality = row-mean of memory bank (8 loads in flight) ----
__global__ __launch_bounds__(256)
void cent_kernel(const float* __restrict__ mem, float* __restrict__ cent, int M) {
    __shared__ float s[4];
    const int row = blockIdx.x;
    const float4* p = (const float4*)(mem + (size_t)row * M);
    const int n4 = M >> 2;
    float acc = 0.0f;
    int i = threadIdx.x;
    for (; i + 1792 < n4; i += 2048) {
        float4 q0 = p[i], q1 = p[i + 256], q2 = p[i + 512], q3 = p[i + 768];
        float4 q4 = p[i + 1024], q5 = p[i + 1280], q6 = p[i + 1536], q7 = p[i + 1792];
        acc += ((q0.x + q0.y) + (q0.z + q0.w)) + ((q1.x + q1.y) + (q1.z + q1.w))
             + ((q2.x + q2.y) + (q2.z + q2.w)) + ((q3.x + q3.y) + (q3.z + q3.w))
             + ((q4.x + q4.y) + (q4.z + q4.w)) + ((q5.x + q5.y) + (q5.z + q5.w))
             + ((q6.x + q6.y) + (q6.z + q6.w)) + ((q7.x + q7.y) + (q7.z + q7.w));
    }
    for (; i < n4; i += 256) {
        float4 q = p[i];
        acc += (q.x + q.y) + (q.z + q.w);
    }
    acc = wave_sum_f(acc);
    const int lane = threadIdx.x & 63, wid = threadIdx.x >> 6;
    if (lane == 0) s[wid] = acc;
    __syncthreads();
    if (threadIdx.x == 0) cent[row] = (s[0] + s[1] + s[2] + s[3]) / (float)M;
}

// ---- per-row loss -> per_row[row]. One 256-thread block per row.
//      Requires B==4096, k<=63. ----
__global__ __launch_bounds__(256)
void row_loss_kernel(const float* __restrict__ sim,
                     const float* __restrict__ cent,
                     const int* __restrict__ knn,
                     const float* __restrict__ temp_p,
                     float* __restrict__ per_row, int B) {
    __shared__ __align__(16) unsigned long long cand[CAP];
    __shared__ unsigned long long s_sel[64];
    __shared__ unsigned long long s_p33;
    __shared__ unsigned int s_kmin[4];
    __shared__ float s_cmin[4], s_cmax[4];
    __shared__ float s_cmin2[4], s_cmax2[4];
    __shared__ unsigned int s_cnt;
    __shared__ float s_diag;

    const int row = blockIdx.x, tid = threadIdx.x;
    const int lane = tid & 63, wid = tid >> 6;
    const int   k    = knn[0];
    const float temp = temp_p[0];

    // --- load row (float4-coalesced), order keys; diag -> key 0 ---
    unsigned int keys[16];
    unsigned int kmin = 0xFFFFFFFFu;
    const float4* rp = (const float4*)(sim + (size_t)row * B);
#pragma unroll
    for (int c = 0; c < 4; ++c) {
        float4 q = rp[c * 256 + tid];
        float t[4] = {q.x, q.y, q.z, q.w};
#pragma unroll
        for (int m = 0; m < 4; ++m) {
            const int j = c * 1024 + tid * 4 + m;
            unsigned int key = f_to_key(t[m]);
            if (j == row) { s_diag = t[m]; key = 0u; }
            else if (key < kmin) kmin = key;
            keys[c * 4 + m] = key;
        }
    }
    { unsigned int w = wave_min_u32(kmin); if (lane == 0) s_kmin[wid] = w; }
    if (tid == 0) { s_cnt = 0; s_p33 = ((unsigned long long)1u) << 32; }

    // --- fused pass: gather candidates (key > keyT) + cent min/max over rest.
    //     First-guess threshold 2.0 puts count in [k+1, CAP] with huge margin
    //     for N(0,1) rows -> 1 pass; bisection fallback keeps it exact. ---
    unsigned int keyT = f_to_key(2.0f), loK = 0u, hiK = 0xFFFFFFFFu, cnt = 0;
    const unsigned int need = (unsigned int)k + 1u;
    float cmin, cmax;
    const float4* cp = (const float4*)cent;
    for (int it = 0; it < MAXIT; ++it) {
        cmin = INFINITY; cmax = -INFINITY;
        __syncthreads();                    // s_cnt (re)set visible
#pragma unroll
        for (int c = 0; c < 4; ++c) {
            float4 q = cp[c * 256 + tid];
            float t[4] = {q.x, q.y, q.z, q.w};
#pragma unroll
            for (int m = 0; m < 4; ++m) {
                const unsigned int key = keys[c * 4 + m];
                if (key == 0u) continue;    // diag: excluded everywhere
                if (key > keyT) {
                    const unsigned int pos = atomicAdd(&s_cnt, 1u);
                    if (pos < CAP)
                        cand[pos] = ((unsigned long long)key << 32) |
                                    (unsigned long long)(0xFFFFFFFFu -
                                        (unsigned int)(c * 1024 + tid * 4 + m));
                } else {
                    cmin = fminf(cmin, t[m]);
                    cmax = fmaxf(cmax, t[m]);
                }
            }
        }
        { float a = wave_min_f(cmin), b = wave_max_f(cmax);
          if (lane == 0) { s_cmin[wid] = a; s_cmax[wid] = b; } }
        __syncthreads();                    // cand/cnt/cmin/cmax visible
        cnt = s_cnt;
        if (cnt >= need && cnt <= CAP) break;
        if (cnt < need) { hiK = keyT; keyT = loK + ((keyT - loK) >> 1); }
        else            { loK = keyT; keyT = keyT + ((hiK - keyT) >> 1); }
        if (tid == 0) s_cnt = 0;
    }

    // --- block-wide exact rank: thread t owns cand[t] (n <= CAP == 256) ---
    {
        const unsigned int n = min(cnt, (unsigned int)CAP);
        const unsigned int uk = (unsigned int)k;
        unsigned long long own = 0ull;
        if ((unsigned int)tid < n) own = cand[tid];
        unsigned int r = 0;
        const ulonglong2* c2 = (const ulonglong2*)cand;   // broadcast b128 reads
        const unsigned int np = n >> 1;
        for (unsigned int o = 0; o < np; ++o) {
            ulonglong2 pr = c2[o];
            r += (pr.x > own) ? 1u : 0u;
            r += (pr.y > own) ? 1u : 0u;
        }
        if (n & 1u) r += (cand[n - 1u] > own) ? 1u : 0u;

        // selected: rank < k; rank == k is the (k+1)-th largest (mx_s);
        // rank >= k candidates re-enter centrality min/max
        float cmin2 = INFINITY, cmax2 = -INFINITY;
        if ((unsigned int)tid < n) {
            if (r < uk) s_sel[r] = own;
            else if (r == uk) s_p33 = own;
            if (r >= uk) {
                const int jj = (int)(0xFFFFFFFFu - (unsigned int)own);
                const float cv = cent[jj];
                cmin2 = fminf(cmin2, cv);
                cmax2 = fmaxf(cmax2, cv);
            }
        }
        cmin2 = wave_min_f(cmin2);
        cmax2 = wave_max_f(cmax2);
        if (lane == 0) { s_cmin2[wid] = cmin2; s_cmax2[wid] = cmax2; }
        __syncthreads();                    // s_sel/s_p33/s_cmin2 visible
    }
    if (wid != 0) return;                   // waves 1-3 done

    // --- wave 0: finale (math identical to validated kernel) ---
    {
        const float mn_c = fminf(
            fminf(fminf(s_cmin2[0], s_cmin2[1]), fminf(s_cmin2[2], s_cmin2[3])),
            fminf(fminf(s_cmin[0], s_cmin[1]), fminf(s_cmin[2], s_cmin[3])));
        const float mx_c = fmaxf(
            fmaxf(fmaxf(s_cmax2[0], s_cmax2[1]), fmaxf(s_cmax2[2], s_cmax2[3])),
            fmaxf(fmaxf(s_cmax[0], s_cmax[1]), fmaxf(s_cmax[2], s_cmax[3])));
        const unsigned int kminb =
            min(min(s_kmin[0], s_kmin[1]), min(s_kmin[2], s_kmin[3]));
        const float mn_s = key_to_f(kminb);
        const float mx_s = key_to_f((unsigned int)(s_p33 >> 32));

        const float sdiag = s_diag;
        const bool  act = (lane < k);
        const unsigned long long sel = act ? s_sel[lane] : 0ull;
        const float sj = act ? key_to_f((unsigned int)(sel >> 32)) : -INFINITY;
        const int   j  = act ? (int)(0xFFFFFFFFu - (unsigned int)sel) : 0;
        const float cj = cent[j];

        float a = -INFINITY;
        if (act) {
            const float ns = (sj - mn_s) / (mx_s - mn_s);
            const float nc = (cj - mn_c) / (mx_c - mn_c);
            a = (ns - nc) * temp;
        }
        const float am   = wave_max_f(a);
        const float e    = act ? expf(a - am) : 0.0f;
        const float esum = wave_sum_f(e);
        const float pw   = e / esum;

        const float m2  = fmaxf(wave_max_f(sj), sdiag);
        const float ex  = act ? expf(sj - m2) : 0.0f;
        const float lse = m2 + logf(wave_sum_f(ex) + expf(sdiag - m2));

        const float num = wave_sum_f(act ? pw * (sj - lse) : 0.0f) + (sdiag - lse);
        const float den = 1.0f + wave_sum_f(pw);
        if (lane == 0) per_row[row] = -num / den;
    }
}

// ---- final mean over per_row -> out[0] ----
__global__ __launch_bounds__(256)
void reduce_kernel(const float* __restrict__ per_row, float* __restrict__ out, int B) {
    __shared__ float s[4];
    float acc = 0.0f;
    const float4* p = (const float4*)per_row;
    const int n4 = B >> 2;
    for (int i = threadIdx.x; i < n4; i += 256) {
        float4 q = p[i];
        acc += (q.x + q.y) + (q.z + q.w);
    }
    acc = wave_sum_f(acc);
    const int lane = threadIdx.x & 63, wid = threadIdx.x >> 6;
    if (lane == 0) s[wid] = acc;
    __syncthreads();
    if (threadIdx.x == 0) out[0] = (s[0] + s[1] + s[2] + s[3]) / (float)B;
}

extern "C" void kernel_launch(void* const* d_in, const int* in_sizes, int n_in,
                              void* d_out, int out_size, void* d_ws, size_t ws_size,
                              hipStream_t stream) {
    const float* sim  = (const float*)d_in[0];
    const float* mem  = (const float*)d_in[1];
    const int*   knn  = (const int*)d_in[2];
    const float* temp = (const float*)d_in[3];
    float* out     = (float*)d_out;
    float* cent    = (float*)d_ws;                 // B floats
    float* per_row = (float*)d_ws + 4096;          // B floats

    const int B = (int)(std::sqrt((double)in_sizes[0]) + 0.5);
    const int M = in_sizes[1] / B;

    cent_kernel<<<B, 256, 0, stream>>>(mem, cent, M);
    row_loss_kernel<<<B, 256, 0, stream>>>(sim, cent, knn, temp, per_row, B);
    reduce_kernel<<<1, 256, 0, stream>>>(per_row, out, B);
}